// Round 1
// baseline (730.265 us; speedup 1.0000x reference)
//
#include <hip/hip_runtime.h>

// Problem constants
constexpr int Sdim = 2048;
constexpr int Bdim = 64;
constexpr int Hdim = 1024;
constexpr int NCHUNK = 16;   // s-chunks per b in K1 (128 s each)
constexpr int KS1 = 16;      // fc1 k-split: K=2048 -> slices of 128
constexpr int KS2 = 8;       // fc2 k-split: K=1024 -> slices of 128

// Workspace layout (float offsets). Total ~10.6 MiB.
constexpr int PM_OFF   = 0;                                 // 1024  partial max per (b,chunk)
constexpr int PL_OFF   = 1024;                              // 1024  partial l
constexpr int PACC_OFF = 2048;                              // 64*16*1024 partial weighted sums
constexpr int ATTN_OFF = PACC_OFF + Bdim * NCHUNK * Hdim;   // 64*1024 attn result
constexpr int XMID_OFF = ATTN_OFF + Bdim * Hdim;            // 64*1024 tanh(BN(fc1)) transposed [o][b]
constexpr int P1_OFF   = XMID_OFF + Bdim * Hdim;            // KS1*64*1024 fc1 k-partials
constexpr int P2_OFF   = P1_OFF + KS1 * Bdim * Hdim;        // KS2*64*1024 fc2 k-partials

// ---------------------------------------------------------------------------
// K1: one-pass attention. Each wave handles 32 s-rows of one b with online
// softmax; 4 waves/block combine via LDS into one partial per (b, chunk).
// Raw (masked) scores are written to the At region of d_out as scratch.
// ---------------------------------------------------------------------------
__global__ __launch_bounds__(256) void k1_attn(const float* __restrict__ ctx,
                                               const float* __restrict__ key,
                                               const float* __restrict__ mask,
                                               float* __restrict__ ws,
                                               float* __restrict__ At) {
    const int chunk = blockIdx.x;    // 0..15
    const int b     = blockIdx.y;    // 0..63
    const int t     = threadIdx.x;
    const int lane  = t & 63;
    const int wave  = t >> 6;

    // key fragment: h = j*256 + lane*4 .. +3
    const float4* key4 = (const float4*)(key + (size_t)b * Hdim);
    float4 kr[4];
#pragma unroll
    for (int j = 0; j < 4; ++j) kr[j] = key4[j * 64 + lane];

    float4 acc[4];
#pragma unroll
    for (int j = 0; j < 4; ++j) acc[j] = make_float4(0.f, 0.f, 0.f, 0.f);
    float m = -1e30f, l = 0.f;

    const int s0 = chunk * 128 + wave * 32;
    for (int i = 0; i < 32; ++i) {
        const int s = s0 + i;
        const float4* c4 = (const float4*)ctx + (((size_t)s * Bdim + b) << 8);
        float4 v[4];
#pragma unroll
        for (int j = 0; j < 4; ++j) v[j] = c4[j * 64 + lane];

        float d = 0.f;
#pragma unroll
        for (int j = 0; j < 4; ++j)
            d += v[j].x * kr[j].x + v[j].y * kr[j].y + v[j].z * kr[j].z + v[j].w * kr[j].w;
#pragma unroll
        for (int off = 32; off >= 1; off >>= 1) d += __shfl_xor(d, off, 64);
        d += mask[b * Sdim + s];
        if (lane == 0) At[b * Sdim + s] = d;   // raw score stash

        const float nm = fmaxf(m, d);
        const float sc = __expf(m - nm);
        const float w  = __expf(d - nm);
#pragma unroll
        for (int j = 0; j < 4; ++j) {
            acc[j].x = acc[j].x * sc + v[j].x * w;
            acc[j].y = acc[j].y * sc + v[j].y * w;
            acc[j].z = acc[j].z * sc + v[j].z * w;
            acc[j].w = acc[j].w * sc + v[j].w * w;
        }
        l = l * sc + w;
        m = nm;
    }

    // combine 4 waves
    __shared__ float lm[4], ll[4];
    __shared__ __align__(16) float lacc[4][1024];
    if (lane == 0) { lm[wave] = m; ll[wave] = l; }
    __syncthreads();
    const float M  = fmaxf(fmaxf(lm[0], lm[1]), fmaxf(lm[2], lm[3]));
    const float scw = __expf(m - M);   // wave-uniform
    float4* lw = (float4*)lacc[wave];
#pragma unroll
    for (int j = 0; j < 4; ++j)
        lw[j * 64 + lane] = make_float4(acc[j].x * scw, acc[j].y * scw,
                                        acc[j].z * scw, acc[j].w * scw);
    __syncthreads();

    const float L = ll[0] * __expf(lm[0] - M) + ll[1] * __expf(lm[1] - M)
                  + ll[2] * __expf(lm[2] - M) + ll[3] * __expf(lm[3] - M);
    const float4* l4 = (const float4*)lacc;   // [4][256] float4
    float4 r = l4[t];
#pragma unroll
    for (int wv = 1; wv < 4; ++wv) {
        float4 o = l4[wv * 256 + t];
        r.x += o.x; r.y += o.y; r.z += o.z; r.w += o.w;
    }
    ((float4*)(ws + PACC_OFF))[(b * NCHUNK + chunk) * 256 + t] = r;
    if (t == 0) {
        ws[PM_OFF + b * NCHUNK + chunk] = M;
        ws[PL_OFF + b * NCHUNK + chunk] = L;
    }
}

// ---------------------------------------------------------------------------
// K2: per-b merge of 16 chunk partials -> attn[b,:], and finalize At in place.
// ---------------------------------------------------------------------------
__global__ __launch_bounds__(256) void k2_final(float* __restrict__ ws,
                                                float* __restrict__ At) {
    const int b = blockIdx.x;
    const int t = threadIdx.x;

    float pm[NCHUNK];
    float M = -1e30f;
#pragma unroll
    for (int c = 0; c < NCHUNK; ++c) {
        pm[c] = ws[PM_OFF + b * NCHUNK + c];
        M = fmaxf(M, pm[c]);
    }
    float e[NCHUNK];
    float L = 0.f;
#pragma unroll
    for (int c = 0; c < NCHUNK; ++c) {
        e[c] = __expf(pm[c] - M);
        L += ws[PL_OFF + b * NCHUNK + c] * e[c];
    }
    const float invL = 1.f / L;

    const float4* pa = (const float4*)(ws + PACC_OFF);
    float4 r = make_float4(0.f, 0.f, 0.f, 0.f);
#pragma unroll
    for (int c = 0; c < NCHUNK; ++c) {
        float4 v = pa[(b * NCHUNK + c) * 256 + t];
        r.x += v.x * e[c]; r.y += v.y * e[c]; r.z += v.z * e[c]; r.w += v.w * e[c];
    }
    r.x *= invL; r.y *= invL; r.z *= invL; r.w *= invL;
    ((float4*)(ws + ATTN_OFF))[b * 256 + t] = r;

#pragma unroll
    for (int k = 0; k < Sdim / 256; ++k) {
        const int s = t + k * 256;
        At[b * Sdim + s] = __expf(At[b * Sdim + s] - M) * invL;
    }
}

// ---------------------------------------------------------------------------
// K3a: fc1 split-K GEMM. x = [attn | key] (virtual concat), w = fc1_w (1024x2048).
// Block: 64 b x 64 o tile, k-slice of 128. 4x4 register micro-tile per thread.
// ---------------------------------------------------------------------------
__global__ __launch_bounds__(256) void k3a_fc1(const float* __restrict__ attn,
                                               const float* __restrict__ key,
                                               const float* __restrict__ w,
                                               float* __restrict__ part) {
    const int obase = blockIdx.x * 64;
    const int kblk  = blockIdx.y;               // 0..KS1-1
    const int t  = threadIdx.x;
    const int bx = (t & 15) * 4;
    const int ox = (t >> 4) * 4;

    __shared__ __align__(16) float xs[32][68];
    __shared__ __align__(16) float wsh[32][68];

    float a[4][4];
#pragma unroll
    for (int i = 0; i < 4; ++i)
#pragma unroll
        for (int j = 0; j < 4; ++j) a[i][j] = 0.f;

    for (int c = 0; c < 4; ++c) {               // 4 chunks of 32 = slice 128
        const int i0 = kblk * 128 + c * 32;
        const float* src = (i0 < Hdim) ? (attn + i0) : (key + (i0 - Hdim));
#pragma unroll
        for (int j = 0; j < 8; ++j) {
            const int e = t + j * 256;
            const int k_l = e & 31, b_l = e >> 5;
            xs[k_l][b_l] = src[b_l * Hdim + k_l];
        }
#pragma unroll
        for (int j = 0; j < 8; ++j) {
            const int e = t + j * 256;
            const int k_l = e & 31, o_l = e >> 5;
            wsh[k_l][o_l] = w[(size_t)(obase + o_l) * 2048 + i0 + k_l];
        }
        __syncthreads();
#pragma unroll
        for (int k = 0; k < 32; ++k) {
            const float4 xv = *(const float4*)&xs[k][bx];
            const float4 wv = *(const float4*)&wsh[k][ox];
            a[0][0] += xv.x * wv.x; a[0][1] += xv.x * wv.y; a[0][2] += xv.x * wv.z; a[0][3] += xv.x * wv.w;
            a[1][0] += xv.y * wv.x; a[1][1] += xv.y * wv.y; a[1][2] += xv.y * wv.z; a[1][3] += xv.y * wv.w;
            a[2][0] += xv.z * wv.x; a[2][1] += xv.z * wv.y; a[2][2] += xv.z * wv.z; a[2][3] += xv.z * wv.w;
            a[3][0] += xv.w * wv.x; a[3][1] += xv.w * wv.y; a[3][2] += xv.w * wv.z; a[3][3] += xv.w * wv.w;
        }
        __syncthreads();
    }
    float* p = part + (size_t)kblk * (Bdim * Hdim);
#pragma unroll
    for (int i = 0; i < 4; ++i)
        *(float4*)&p[(bx + i) * Hdim + obase + ox] = make_float4(a[i][0], a[i][1], a[i][2], a[i][3]);
}

// ---------------------------------------------------------------------------
// K3b: reduce fc1 partials + bias, BatchNorm (batch stats via 64-lane wave
// reduction: one wave = all 64 batch rows), tanh; store transposed [o][b].
// ---------------------------------------------------------------------------
__global__ __launch_bounds__(256) void k3b_bn(const float* __restrict__ p1,
                                              const float* __restrict__ fc1_b,
                                              const float* __restrict__ gamma,
                                              const float* __restrict__ beta,
                                              float* __restrict__ xmidT) {
    const int obase = blockIdx.x * 16;
    const int t  = threadIdx.x;
    const int b  = t & 63;
    const int ot = t >> 6;
    const int o0 = obase + ot * 4;

    float4 acc = ((const float4*)fc1_b)[o0 >> 2];
    const float4* p4 = (const float4*)p1;
#pragma unroll
    for (int k = 0; k < KS1; ++k) {
        float4 v = p4[k * (Bdim * Hdim / 4) + b * (Hdim / 4) + (o0 >> 2)];
        acc.x += v.x; acc.y += v.y; acc.z += v.z; acc.w += v.w;
    }
    const float4 g  = ((const float4*)gamma)[o0 >> 2];
    const float4 be = ((const float4*)beta)[o0 >> 2];
    const float xv[4] = {acc.x, acc.y, acc.z, acc.w};
    const float gv[4] = {g.x, g.y, g.z, g.w};
    const float bv[4] = {be.x, be.y, be.z, be.w};
#pragma unroll
    for (int q = 0; q < 4; ++q) {
        const float x = xv[q];
        float s1 = x, s2 = x * x;
#pragma unroll
        for (int off = 32; off >= 1; off >>= 1) {
            s1 += __shfl_xor(s1, off, 64);
            s2 += __shfl_xor(s2, off, 64);
        }
        const float mean = s1 * (1.f / 64.f);
        float var = s2 * (1.f / 64.f) - mean * mean;
        var = fmaxf(var, 0.f);
        const float inv = rsqrtf(var + 1e-5f);
        const float y = (x - mean) * inv * gv[q] + bv[q];
        xmidT[(o0 + q) * Bdim + b] = tanhf(y);
    }
}

// ---------------------------------------------------------------------------
// K4a: fc2 split-K GEMM. Input xmidT is [k][b] (transposed), w = fc2_w (1024x1024).
// ---------------------------------------------------------------------------
__global__ __launch_bounds__(256) void k4a_fc2(const float* __restrict__ xmidT,
                                               const float* __restrict__ w,
                                               float* __restrict__ part) {
    const int obase = blockIdx.x * 64;
    const int kblk  = blockIdx.y;               // 0..KS2-1
    const int t  = threadIdx.x;
    const int bx = (t & 15) * 4;
    const int ox = (t >> 4) * 4;

    __shared__ __align__(16) float xs[32][68];
    __shared__ __align__(16) float wsh[32][68];

    float a[4][4];
#pragma unroll
    for (int i = 0; i < 4; ++i)
#pragma unroll
        for (int j = 0; j < 4; ++j) a[i][j] = 0.f;

    for (int c = 0; c < 4; ++c) {
        const int i0 = kblk * 128 + c * 32;
#pragma unroll
        for (int j = 0; j < 8; ++j) {
            const int e = t + j * 256;
            const int k_l = e >> 6, b_l = e & 63;
            xs[k_l][b_l] = xmidT[(i0 + k_l) * Bdim + b_l];
        }
#pragma unroll
        for (int j = 0; j < 8; ++j) {
            const int e = t + j * 256;
            const int k_l = e & 31, o_l = e >> 5;
            wsh[k_l][o_l] = w[(size_t)(obase + o_l) * Hdim + i0 + k_l];
        }
        __syncthreads();
#pragma unroll
        for (int k = 0; k < 32; ++k) {
            const float4 xv = *(const float4*)&xs[k][bx];
            const float4 wv = *(const float4*)&wsh[k][ox];
            a[0][0] += xv.x * wv.x; a[0][1] += xv.x * wv.y; a[0][2] += xv.x * wv.z; a[0][3] += xv.x * wv.w;
            a[1][0] += xv.y * wv.x; a[1][1] += xv.y * wv.y; a[1][2] += xv.y * wv.z; a[1][3] += xv.y * wv.w;
            a[2][0] += xv.z * wv.x; a[2][1] += xv.z * wv.y; a[2][2] += xv.z * wv.z; a[2][3] += xv.z * wv.w;
            a[3][0] += xv.w * wv.x; a[3][1] += xv.w * wv.y; a[3][2] += xv.w * wv.z; a[3][3] += xv.w * wv.w;
        }
        __syncthreads();
    }
    float* p = part + (size_t)kblk * (Bdim * Hdim);
#pragma unroll
    for (int i = 0; i < 4; ++i)
        *(float4*)&p[(bx + i) * Hdim + obase + ox] = make_float4(a[i][0], a[i][1], a[i][2], a[i][3]);
}

// ---------------------------------------------------------------------------
// K4b: reduce fc2 partials + bias -> final x output (coalesced).
// ---------------------------------------------------------------------------
__global__ __launch_bounds__(256) void k4b_out(const float* __restrict__ p2,
                                               const float* __restrict__ fc2_b,
                                               float* __restrict__ outx) {
    const int idx = blockIdx.x * 256 + threadIdx.x;   // 0..65535
    float v = fc2_b[idx & (Hdim - 1)];
#pragma unroll
    for (int k = 0; k < KS2; ++k) v += p2[k * (Bdim * Hdim) + idx];
    outx[idx] = v;
}

extern "C" void kernel_launch(void* const* d_in, const int* in_sizes, int n_in,
                              void* d_out, int out_size, void* d_ws, size_t ws_size,
                              hipStream_t stream) {
    const float* ctx    = (const float*)d_in[0];
    const float* key    = (const float*)d_in[1];
    const float* mask   = (const float*)d_in[2];
    const float* fc1_w  = (const float*)d_in[3];
    const float* fc1_b  = (const float*)d_in[4];
    const float* gamma  = (const float*)d_in[5];
    const float* beta   = (const float*)d_in[6];
    const float* fc2_w  = (const float*)d_in[7];
    const float* fc2_b  = (const float*)d_in[8];

    float* outx = (float*)d_out;               // (64,1024)
    float* At   = outx + Bdim * Hdim;          // (64,2048)
    float* ws   = (float*)d_ws;

    k1_attn<<<dim3(NCHUNK, Bdim), 256, 0, stream>>>(ctx, key, mask, ws, At);
    k2_final<<<Bdim, 256, 0, stream>>>(ws, At);
    k3a_fc1<<<dim3(Hdim / 64, KS1), 256, 0, stream>>>(ws + ATTN_OFF, key, fc1_w, ws + P1_OFF);
    k3b_bn<<<Hdim / 16, 256, 0, stream>>>(ws + P1_OFF, fc1_b, gamma, beta, ws + XMID_OFF);
    k4a_fc2<<<dim3(Hdim / 64, KS2), 256, 0, stream>>>(ws + XMID_OFF, fc2_w, ws + P2_OFF);
    k4b_out<<<Bdim * Hdim / 256, 256, 0, stream>>>(ws + P2_OFF, fc2_b, outx);
}

// Round 3
// 704.127 us; speedup vs baseline: 1.0371x; 1.0371x over previous
//
#include <hip/hip_runtime.h>

typedef float nf4 __attribute__((ext_vector_type(4)));   // native vec for nontemporal builtins

// Problem constants
constexpr int Sdim = 2048;
constexpr int Bdim = 64;
constexpr int Hdim = 1024;
constexpr int NCHUNK = 32;   // s-chunks per b in K1 (64 s each, 16 s per wave)
constexpr int KS1 = 16;      // fc1 k-split: K=2048 -> slices of 128
constexpr int KS2 = 8;       // fc2 k-split: K=1024 -> slices of 128

// Workspace layout (float offsets). Total ~14.6 MiB.
constexpr int PM_OFF   = 0;                                 // 2048  partial max per (b,chunk)
constexpr int PL_OFF   = PM_OFF + Bdim * NCHUNK;            // 2048  partial l
constexpr int PACC_OFF = PL_OFF + Bdim * NCHUNK;            // 64*32*1024 partial weighted sums
constexpr int ATTN_OFF = PACC_OFF + Bdim * NCHUNK * Hdim;   // 64*1024 attn result
constexpr int XMID_OFF = ATTN_OFF + Bdim * Hdim;            // 64*1024 tanh(BN(fc1)) transposed [o][b]
constexpr int P1_OFF   = XMID_OFF + Bdim * Hdim;            // KS1*64*1024 fc1 k-partials
constexpr int P2_OFF   = P1_OFF + KS1 * Bdim * Hdim;        // KS2*64*1024 fc2 k-partials

// ---------------------------------------------------------------------------
// K1: one-pass attention, 2 s-rows per iteration (doubles loads in flight,
// halves the serial online-softmax chain). Each wave owns 16 s-rows of one b;
// 4 waves/block combine via LDS into one partial per (b, chunk).
// Raw (masked) scores stash into the At region of d_out.
// ---------------------------------------------------------------------------
__global__ __launch_bounds__(256) void k1_attn(const float* __restrict__ ctx,
                                               const float* __restrict__ key,
                                               const float* __restrict__ mask,
                                               float* __restrict__ ws,
                                               float* __restrict__ At) {
    const int chunk = blockIdx.x;    // 0..31
    const int b     = blockIdx.y;    // 0..63
    const int t     = threadIdx.x;
    const int lane  = t & 63;
    const int wave  = t >> 6;

    // key fragment: h = j*256 + lane*4 .. +3
    const nf4* key4 = (const nf4*)(key + (size_t)b * Hdim);
    nf4 kr[4];
#pragma unroll
    for (int j = 0; j < 4; ++j) kr[j] = key4[j * 64 + lane];

    nf4 acc[4];
#pragma unroll
    for (int j = 0; j < 4; ++j) acc[j] = (nf4)(0.f);
    float m = -1e30f, l = 0.f;

    const int s0 = chunk * 64 + wave * 16;
    for (int i = 0; i < 8; ++i) {
        const int sa = s0 + 2 * i;
        const int sb = sa + 1;
        const nf4* ca = (const nf4*)ctx + (((size_t)sa * Bdim + b) << 8);
        const nf4* cb = (const nf4*)ctx + (((size_t)sb * Bdim + b) << 8);
        nf4 va[4], vb[4];
#pragma unroll
        for (int j = 0; j < 4; ++j) va[j] = __builtin_nontemporal_load(&ca[j * 64 + lane]);
#pragma unroll
        for (int j = 0; j < 4; ++j) vb[j] = __builtin_nontemporal_load(&cb[j * 64 + lane]);

        float da = 0.f, db = 0.f;
#pragma unroll
        for (int j = 0; j < 4; ++j) {
            da += va[j].x * kr[j].x + va[j].y * kr[j].y + va[j].z * kr[j].z + va[j].w * kr[j].w;
            db += vb[j].x * kr[j].x + vb[j].y * kr[j].y + vb[j].z * kr[j].z + vb[j].w * kr[j].w;
        }
#pragma unroll
        for (int off = 32; off >= 1; off >>= 1) {
            da += __shfl_xor(da, off, 64);
            db += __shfl_xor(db, off, 64);
        }
        da += mask[b * Sdim + sa];
        db += mask[b * Sdim + sb];
        if (lane == 0) {
            At[b * Sdim + sa] = da;   // raw score stash
            At[b * Sdim + sb] = db;
        }

        const float nm = fmaxf(m, fmaxf(da, db));
        const float sc = __expf(m - nm);
        const float wa = __expf(da - nm);
        const float wb = __expf(db - nm);
#pragma unroll
        for (int j = 0; j < 4; ++j)
            acc[j] = acc[j] * sc + va[j] * wa + vb[j] * wb;
        l = l * sc + wa + wb;
        m = nm;
    }

    // combine 4 waves
    __shared__ float lm[4], ll[4];
    __shared__ __align__(16) float lacc[4][1024];
    if (lane == 0) { lm[wave] = m; ll[wave] = l; }
    __syncthreads();
    const float M  = fmaxf(fmaxf(lm[0], lm[1]), fmaxf(lm[2], lm[3]));
    const float scw = __expf(m - M);   // wave-uniform
    nf4* lw = (nf4*)lacc[wave];
#pragma unroll
    for (int j = 0; j < 4; ++j)
        lw[j * 64 + lane] = acc[j] * scw;
    __syncthreads();

    const float L = ll[0] * __expf(lm[0] - M) + ll[1] * __expf(lm[1] - M)
                  + ll[2] * __expf(lm[2] - M) + ll[3] * __expf(lm[3] - M);
    const nf4* l4 = (const nf4*)lacc;   // [4][256] nf4
    nf4 r = l4[t];
#pragma unroll
    for (int wv = 1; wv < 4; ++wv)
        r += l4[wv * 256 + t];
    ((nf4*)(ws + PACC_OFF))[(b * NCHUNK + chunk) * 256 + t] = r;
    if (t == 0) {
        ws[PM_OFF + b * NCHUNK + chunk] = M;
        ws[PL_OFF + b * NCHUNK + chunk] = L;
    }
}

// ---------------------------------------------------------------------------
// K2: per-b merge of 32 chunk partials -> attn[b,:], and finalize At in place.
// ---------------------------------------------------------------------------
__global__ __launch_bounds__(256) void k2_final(float* __restrict__ ws,
                                                float* __restrict__ At) {
    const int b = blockIdx.x;
    const int t = threadIdx.x;

    float M = -1e30f;
#pragma unroll
    for (int c = 0; c < NCHUNK; ++c)
        M = fmaxf(M, ws[PM_OFF + b * NCHUNK + c]);
    float L = 0.f;
#pragma unroll
    for (int c = 0; c < NCHUNK; ++c)
        L += ws[PL_OFF + b * NCHUNK + c] * __expf(ws[PM_OFF + b * NCHUNK + c] - M);
    const float invL = 1.f / L;

    const nf4* pa = (const nf4*)(ws + PACC_OFF);
    nf4 r = (nf4)(0.f);
#pragma unroll
    for (int c = 0; c < NCHUNK; ++c) {
        const float e = __expf(ws[PM_OFF + b * NCHUNK + c] - M);
        r += pa[(b * NCHUNK + c) * 256 + t] * e;
    }
    r *= invL;
    ((nf4*)(ws + ATTN_OFF))[b * 256 + t] = r;

    // finalize At: 2048 floats per b = 512 float4, 2 per thread
    nf4* At4 = (nf4*)(At + b * Sdim);
#pragma unroll
    for (int k = 0; k < 2; ++k) {
        nf4 v = At4[t + k * 256];
        v.x = __expf(v.x - M) * invL;
        v.y = __expf(v.y - M) * invL;
        v.z = __expf(v.z - M) * invL;
        v.w = __expf(v.w - M) * invL;
        At4[t + k * 256] = v;
    }
}

// ---------------------------------------------------------------------------
// K3a: fc1 split-K GEMM. x = [attn | key] (virtual concat), w = fc1_w (1024x2048).
// Block: 64 b x 64 o tile, k-slice of 128. 4x4 register micro-tile per thread.
// ---------------------------------------------------------------------------
__global__ __launch_bounds__(256) void k3a_fc1(const float* __restrict__ attn,
                                               const float* __restrict__ key,
                                               const float* __restrict__ w,
                                               float* __restrict__ part) {
    const int obase = blockIdx.x * 64;
    const int kblk  = blockIdx.y;               // 0..KS1-1
    const int t  = threadIdx.x;
    const int bx = (t & 15) * 4;
    const int ox = (t >> 4) * 4;

    __shared__ __align__(16) float xs[32][68];
    __shared__ __align__(16) float wsh[32][68];

    float a[4][4];
#pragma unroll
    for (int i = 0; i < 4; ++i)
#pragma unroll
        for (int j = 0; j < 4; ++j) a[i][j] = 0.f;

    for (int c = 0; c < 4; ++c) {               // 4 chunks of 32 = slice 128
        const int i0 = kblk * 128 + c * 32;
        const float* src = (i0 < Hdim) ? (attn + i0) : (key + (i0 - Hdim));
#pragma unroll
        for (int j = 0; j < 8; ++j) {
            const int e = t + j * 256;
            const int k_l = e & 31, b_l = e >> 5;
            xs[k_l][b_l] = src[b_l * Hdim + k_l];
        }
#pragma unroll
        for (int j = 0; j < 8; ++j) {
            const int e = t + j * 256;
            const int k_l = e & 31, o_l = e >> 5;
            wsh[k_l][o_l] = w[(size_t)(obase + o_l) * 2048 + i0 + k_l];
        }
        __syncthreads();
#pragma unroll
        for (int k = 0; k < 32; ++k) {
            const float4 xv = *(const float4*)&xs[k][bx];
            const float4 wv = *(const float4*)&wsh[k][ox];
            a[0][0] += xv.x * wv.x; a[0][1] += xv.x * wv.y; a[0][2] += xv.x * wv.z; a[0][3] += xv.x * wv.w;
            a[1][0] += xv.y * wv.x; a[1][1] += xv.y * wv.y; a[1][2] += xv.y * wv.z; a[1][3] += xv.y * wv.w;
            a[2][0] += xv.z * wv.x; a[2][1] += xv.z * wv.y; a[2][2] += xv.z * wv.z; a[2][3] += xv.z * wv.w;
            a[3][0] += xv.w * wv.x; a[3][1] += xv.w * wv.y; a[3][2] += xv.w * wv.z; a[3][3] += xv.w * wv.w;
        }
        __syncthreads();
    }
    float* p = part + (size_t)kblk * (Bdim * Hdim);
#pragma unroll
    for (int i = 0; i < 4; ++i)
        *(float4*)&p[(bx + i) * Hdim + obase + ox] = make_float4(a[i][0], a[i][1], a[i][2], a[i][3]);
}

// ---------------------------------------------------------------------------
// K3b: reduce fc1 partials + bias, BatchNorm (batch stats via 64-lane wave
// reduction: one wave = all 64 batch rows), tanh; store transposed [o][b].
// ---------------------------------------------------------------------------
__global__ __launch_bounds__(256) void k3b_bn(const float* __restrict__ p1,
                                              const float* __restrict__ fc1_b,
                                              const float* __restrict__ gamma,
                                              const float* __restrict__ beta,
                                              float* __restrict__ xmidT) {
    const int obase = blockIdx.x * 16;
    const int t  = threadIdx.x;
    const int b  = t & 63;
    const int ot = t >> 6;
    const int o0 = obase + ot * 4;

    float4 acc = ((const float4*)fc1_b)[o0 >> 2];
    const float4* p4 = (const float4*)p1;
#pragma unroll
    for (int k = 0; k < KS1; ++k) {
        float4 v = p4[k * (Bdim * Hdim / 4) + b * (Hdim / 4) + (o0 >> 2)];
        acc.x += v.x; acc.y += v.y; acc.z += v.z; acc.w += v.w;
    }
    const float4 g  = ((const float4*)gamma)[o0 >> 2];
    const float4 be = ((const float4*)beta)[o0 >> 2];
    const float xv[4] = {acc.x, acc.y, acc.z, acc.w};
    const float gv[4] = {g.x, g.y, g.z, g.w};
    const float bv[4] = {be.x, be.y, be.z, be.w};
#pragma unroll
    for (int q = 0; q < 4; ++q) {
        const float x = xv[q];
        float s1 = x, s2 = x * x;
#pragma unroll
        for (int off = 32; off >= 1; off >>= 1) {
            s1 += __shfl_xor(s1, off, 64);
            s2 += __shfl_xor(s2, off, 64);
        }
        const float mean = s1 * (1.f / 64.f);
        float var = s2 * (1.f / 64.f) - mean * mean;
        var = fmaxf(var, 0.f);
        const float inv = rsqrtf(var + 1e-5f);
        const float y = (x - mean) * inv * gv[q] + bv[q];
        xmidT[(o0 + q) * Bdim + b] = tanhf(y);
    }
}

// ---------------------------------------------------------------------------
// K4a: fc2 split-K GEMM. Input xmidT is [k][b] (transposed), w = fc2_w (1024x1024).
// ---------------------------------------------------------------------------
__global__ __launch_bounds__(256) void k4a_fc2(const float* __restrict__ xmidT,
                                               const float* __restrict__ w,
                                               float* __restrict__ part) {
    const int obase = blockIdx.x * 64;
    const int kblk  = blockIdx.y;               // 0..KS2-1
    const int t  = threadIdx.x;
    const int bx = (t & 15) * 4;
    const int ox = (t >> 4) * 4;

    __shared__ __align__(16) float xs[32][68];
    __shared__ __align__(16) float wsh[32][68];

    float a[4][4];
#pragma unroll
    for (int i = 0; i < 4; ++i)
#pragma unroll
        for (int j = 0; j < 4; ++j) a[i][j] = 0.f;

    for (int c = 0; c < 4; ++c) {
        const int i0 = kblk * 128 + c * 32;
#pragma unroll
        for (int j = 0; j < 8; ++j) {
            const int e = t + j * 256;
            const int k_l = e >> 6, b_l = e & 63;
            xs[k_l][b_l] = xmidT[(i0 + k_l) * Bdim + b_l];
        }
#pragma unroll
        for (int j = 0; j < 8; ++j) {
            const int e = t + j * 256;
            const int k_l = e & 31, o_l = e >> 5;
            wsh[k_l][o_l] = w[(size_t)(obase + o_l) * Hdim + i0 + k_l];
        }
        __syncthreads();
#pragma unroll
        for (int k = 0; k < 32; ++k) {
            const float4 xv = *(const float4*)&xs[k][bx];
            const float4 wv = *(const float4*)&wsh[k][ox];
            a[0][0] += xv.x * wv.x; a[0][1] += xv.x * wv.y; a[0][2] += xv.x * wv.z; a[0][3] += xv.x * wv.w;
            a[1][0] += xv.y * wv.x; a[1][1] += xv.y * wv.y; a[1][2] += xv.y * wv.z; a[1][3] += xv.y * wv.w;
            a[2][0] += xv.z * wv.x; a[2][1] += xv.z * wv.y; a[2][2] += xv.z * wv.z; a[2][3] += xv.z * wv.w;
            a[3][0] += xv.w * wv.x; a[3][1] += xv.w * wv.y; a[3][2] += xv.w * wv.z; a[3][3] += xv.w * wv.w;
        }
        __syncthreads();
    }
    float* p = part + (size_t)kblk * (Bdim * Hdim);
#pragma unroll
    for (int i = 0; i < 4; ++i)
        *(float4*)&p[(bx + i) * Hdim + obase + ox] = make_float4(a[i][0], a[i][1], a[i][2], a[i][3]);
}

// ---------------------------------------------------------------------------
// K4b: reduce fc2 partials + bias -> final x output (coalesced).
// ---------------------------------------------------------------------------
__global__ __launch_bounds__(256) void k4b_out(const float* __restrict__ p2,
                                               const float* __restrict__ fc2_b,
                                               float* __restrict__ outx) {
    const int idx = blockIdx.x * 256 + threadIdx.x;   // 0..65535
    float v = fc2_b[idx & (Hdim - 1)];
#pragma unroll
    for (int k = 0; k < KS2; ++k) v += p2[k * (Bdim * Hdim) + idx];
    outx[idx] = v;
}

extern "C" void kernel_launch(void* const* d_in, const int* in_sizes, int n_in,
                              void* d_out, int out_size, void* d_ws, size_t ws_size,
                              hipStream_t stream) {
    const float* ctx    = (const float*)d_in[0];
    const float* key    = (const float*)d_in[1];
    const float* mask   = (const float*)d_in[2];
    const float* fc1_w  = (const float*)d_in[3];
    const float* fc1_b  = (const float*)d_in[4];
    const float* gamma  = (const float*)d_in[5];
    const float* beta   = (const float*)d_in[6];
    const float* fc2_w  = (const float*)d_in[7];
    const float* fc2_b  = (const float*)d_in[8];

    float* outx = (float*)d_out;               // (64,1024)
    float* At   = outx + Bdim * Hdim;          // (64,2048)
    float* ws   = (float*)d_ws;

    k1_attn<<<dim3(NCHUNK, Bdim), 256, 0, stream>>>(ctx, key, mask, ws, At);
    k2_final<<<Bdim, 256, 0, stream>>>(ws, At);
    k3a_fc1<<<dim3(Hdim / 64, KS1), 256, 0, stream>>>(ws + ATTN_OFF, key, fc1_w, ws + P1_OFF);
    k3b_bn<<<Hdim / 16, 256, 0, stream>>>(ws + P1_OFF, fc1_b, gamma, beta, ws + XMID_OFF);
    k4a_fc2<<<dim3(Hdim / 64, KS2), 256, 0, stream>>>(ws + XMID_OFF, fc2_w, ws + P2_OFF);
    k4b_out<<<Bdim * Hdim / 256, 256, 0, stream>>>(ws + P2_OFF, fc2_b, outx);
}